// Round 9
// baseline (335.464 us; speedup 1.0000x reference)
//
#include <hip/hip_runtime.h>
#include <math.h>

// Problem constants
#define BATCH 64
#define CIN   32
#define TIN   2048
#define FILT  64
#define WIN   5
#define TP1   2044   // conv1 out
#define TP2   2040   // pool out
#define LOUT  2036   // conv2 out
#define DEMB  256
#define DA    64
#define NSEC  11
#define NC    4      // S chunks
#define CS    509    // l's per chunk (4*509 = 2036)
#define NXB   9      // conv1 x-blocks
#define CT_TILE 252  // pool outputs per conv1 block (63 lanes x 4)
#define NPS   (BATCH * NXB)   // 576 BN partial slots per filter

// ---------------------------------------------------------------------------
// Kernel P: fused prep — zero count, W1 transpose, emb transpose, w1 repack.
// ---------------------------------------------------------------------------
__global__ __launch_bounds__(256) void k_prep(
    const float* __restrict__ W1, const float* __restrict__ emb,
    const float* __restrict__ w1, float* __restrict__ w1t,
    float* __restrict__ embT, float* __restrict__ w1r, int* __restrict__ count) {
  __shared__ float tl[64 * 65];
  int bk = blockIdx.x;
  const int tid = threadIdx.x;
  if (bk < 64) { count[bk * 256 + tid] = 0; return; }
  bk -= 64;
  if (bk < 32) {                       // W1 [64 x 2036] -> w1t [2036 x 64]
    const int l0 = bk * 64;
    const int lc = tid & 63, rq = tid >> 6;
    for (int a = rq; a < 64; a += 4)
      tl[a * 65 + lc] = (l0 + lc < LOUT) ? W1[a * LOUT + l0 + lc] : 0.f;
    __syncthreads();
    for (int lp = rq; lp < 64; lp += 4)
      if (l0 + lp < LOUT) w1t[(l0 + lp) * 64 + lc] = tl[lc * 65 + lp];
    return;
  }
  bk -= 32;
  if (bk < 16) {                       // emb [256 x 256] -> embT [256 x 256]
    const int j0 = (bk & 3) * 64, d0 = (bk >> 2) * 64;
    const int c = tid & 63, rq = tid >> 6;
    for (int j = rq; j < 64; j += 4) tl[j * 65 + c] = emb[(j0 + j) * DEMB + d0 + c];
    __syncthreads();
    for (int d = rq; d < 64; d += 4) embT[(d0 + d) * DEMB + j0 + c] = tl[c * 65 + d];
    return;
  }
  bk -= 16;
  {                                    // w1 [f][c][k] -> w1r [c][f*5+k]
    int i = bk * 256 + tid;            // 40*256 = 10240 exactly
    int c = i / 320, r = i - c * 320, f = r / 5, k = r - f * 5;
    w1r[i] = w1[f * (CIN * WIN) + c * WIN + k];
  }
}

// ---------------------------------------------------------------------------
// Kernel A: conv1 + bias + maxpool(5,1). R15: z-merge retry with
// __launch_bounds__(256, 2). R7's z-merge spilled NOT because 16x4 tiling
// is too big, but because the allocator's occupancy heuristic capped VGPR
// at 44 (< the 64-reg acc tile) when no min-waves hint was given — counters:
// VGPR 44, VALUBusy 38%, scratch round-trips. min-waves=2 lifts the cap to
// 256. Geometry: 16 filters x 4 outputs/wave, grid (9,64); per c-step 2
// x-loads + 320 FMA (640 VALU cyc/wave covers L2 latency even at 2
// waves/SIMD). Weights via wave-uniform s_load (R6). No LDS. BN partial
// stats fused, atomic-free.
// ---------------------------------------------------------------------------
__global__ __launch_bounds__(256, 2) void k_conv1pool(
    const float* __restrict__ x, const float* __restrict__ w1r,
    const float* __restrict__ b1, float* __restrict__ h2,
    double* __restrict__ bn_ps, double* __restrict__ bn_pq) {
  const int b   = blockIdx.y;
  const int t0  = blockIdx.x * CT_TILE;
  const int tid = threadIdx.x;

  const int tg   = tid & 63;
  const int tb   = tg * 4;
  const int wf0  = __builtin_amdgcn_readfirstlane((tid >> 6) * 16);
  // wave-uniform weight base -> scalar (SGPR) address -> s_load weights.
  const float* wp = w1r + __builtin_amdgcn_readfirstlane((tid >> 6) * 80);

  float acc[16][4];
#pragma unroll
  for (int ff = 0; ff < 16; ++ff) {
    float bias = b1[wf0 + ff];
#pragma unroll
    for (int j = 0; j < 4; ++j) acc[ff][j] = bias;
  }

  const float* xrow = x + (size_t)b * CIN * TIN + t0 + tb;
  const bool safe = (t0 + tb + 8) <= TIN;

  for (int c = 0; c < CIN; ++c) {
    float xw[8];
    if (safe) {
      float4 a0 = *(const float4*)(xrow + c * TIN);
      float4 a1 = *(const float4*)(xrow + c * TIN + 4);
      xw[0] = a0.x; xw[1] = a0.y; xw[2] = a0.z; xw[3] = a0.w;
      xw[4] = a1.x; xw[5] = a1.y; xw[6] = a1.z; xw[7] = a1.w;
    } else {
#pragma unroll
      for (int j = 0; j < 8; ++j) {
        int gt = t0 + tb + j;
        xw[j] = (gt < TIN) ? xrow[c * TIN + j] : 0.f;
      }
    }
#pragma unroll
    for (int q = 0; q < 20; ++q) {
      float4 wq = *(const float4*)(wp + c * 320 + q * 4);   // uniform -> s_load
      float wv[4] = {wq.x, wq.y, wq.z, wq.w};
#pragma unroll
      for (int r = 0; r < 4; ++r) {
        const int wi = q * 4 + r;          // compile-time 0..79
        const int ff = wi / 5, k = wi % 5; // static decode
#pragma unroll
        for (int j = 0; j < 4; ++j)
          acc[ff][j] = fmaf(xw[k + j], wv[r], acc[ff][j]);
      }
    }
  }

  const bool lanevalid = (tg < 63);
  const int t2b = t0 + tb;
  const int pslot = b * NXB + blockIdx.x;   // 0..575, unique per (b,bx)
#pragma unroll
  for (int ff = 0; ff < 16; ++ff) {
    float n0 = __shfl_down(acc[ff][0], 1);
    float n1 = __shfl_down(acc[ff][1], 1);
    float n2 = __shfl_down(acc[ff][2], 1);
    float n3 = __shfl_down(acc[ff][3], 1);
    float h[8] = {acc[ff][0], acc[ff][1], acc[ff][2], acc[ff][3],
                  n0, n1, n2, n3};
    float o[4];
#pragma unroll
    for (int j = 0; j < 4; ++j) {
      float m = fmaxf(fmaxf(h[j], h[j + 1]), fmaxf(h[j + 2], h[j + 3]));
      o[j] = fmaxf(m, h[j + 4]);
    }
    const int f = wf0 + ff;

    // fused BN partial stats: wave-reduce fp64, plain store (no atomics)
    double sd = 0.0, qd = 0.0;
    if (lanevalid) {
#pragma unroll
      for (int j = 0; j < 4; ++j) {
        if (t2b + j < TP2) {
          double v = (double)o[j];
          sd += v;
          qd = fma(v, v, qd);
        }
      }
    }
#pragma unroll
    for (int off = 32; off > 0; off >>= 1) {
      sd += __shfl_down(sd, off);
      qd += __shfl_down(qd, off);
    }
    if (tg == 0) {
      bn_ps[f * NPS + pslot] = sd;
      bn_pq[f * NPS + pslot] = qd;
    }

    if (lanevalid && (t2b + 3 < TP2)) {
      float* dst = &h2[((size_t)b * FILT + f) * TP2 + t2b];
      *(float4*)dst = make_float4(o[0], o[1], o[2], o[3]);
    } else if (lanevalid) {
#pragma unroll
      for (int j = 0; j < 4; ++j) {
        int t2 = t2b + j;
        if (t2 < TP2) h2[((size_t)b * FILT + f) * TP2 + t2] = o[j];
      }
    }
  }
}

// ---------------------------------------------------------------------------
// Kernel B2: single-block BN finalize. Reduces the 64xNPS fp64 partials and
// emits the fused conv2 taps ws2g[f*5+k] = sc_f * w2[f,k] and constant c0
// (sum_f sh_f * sum_k w2[f,k] + b2).
// ---------------------------------------------------------------------------
__global__ __launch_bounds__(256) void k_bnfin(
    const double* __restrict__ bn_ps, const double* __restrict__ bn_pq,
    const float* __restrict__ gamma, const float* __restrict__ beta,
    const float* __restrict__ w2, const float* __restrict__ b2,
    double* __restrict__ ws2g, double* __restrict__ c0g) {
  __shared__ double sred[256], qred[256];
  const int tid = threadIdx.x;
  const int f = tid & 63, qq = tid >> 6;
  double s = 0.0, q = 0.0;
  for (int i = qq * (NPS / 4); i < (qq + 1) * (NPS / 4); ++i) {
    s += bn_ps[f * NPS + i];
    q += bn_pq[f * NPS + i];
  }
  sred[tid] = s; qred[tid] = q;
  __syncthreads();
  if (tid < 64) {
    double S = sred[tid] + sred[tid + 64] + sred[tid + 128] + sred[tid + 192];
    double Q = qred[tid] + qred[tid + 64] + qred[tid + 128] + qred[tid + 192];
    const double N = (double)(BATCH * TP2);
    double mu  = S / N;
    double var = Q / N - mu * mu;
    double sc  = (double)gamma[tid] / sqrt(var + 1e-5);
    double sh  = (double)beta[tid] - mu * sc;
    double wsum = 0.0;
#pragma unroll
    for (int k = 0; k < WIN; ++k) {
      double wv = (double)w2[tid * WIN + k];
      ws2g[tid * WIN + k] = sc * wv;
      wsum += wv;
    }
    double part = sh * wsum;
#pragma unroll
    for (int off = 32; off > 0; off >>= 1) part += __shfl_down(part, off);
    if (tid == 0) c0g[0] = part + (double)b2[0];
  }
}

// ---------------------------------------------------------------------------
// Kernel C: conv2 (frozen fp64 precision path). Taps come precomputed from
// k_bnfin; float4 LDS staging.
// ---------------------------------------------------------------------------
__global__ __launch_bounds__(256) void k_conv2(
    const float* __restrict__ h2, const double* __restrict__ ws2g,
    const double* __restrict__ c0g, int* __restrict__ idxp,
    int* __restrict__ count) {
  __shared__ float hl[FILT * 260];
  __shared__ int hist[DEMB];
  __shared__ double ws2l[FILT * WIN];
  __shared__ double c0l;
  const int b = blockIdx.y;
  const int t0 = blockIdx.x * 256;
  const int tid = threadIdx.x;

  for (int i = tid; i < FILT * WIN; i += 256) ws2l[i] = ws2g[i];
  if (tid == 0) c0l = c0g[0];

  // float4 staging: 64 filters x 65 float4 = 260 floats per row
  for (int i = tid; i < FILT * 65; i += 256) {
    int f = i / 65, o4 = (i - f * 65) * 4;
    int gt = t0 + o4;
    const float* src = &h2[((size_t)b * FILT + f) * TP2 + gt];
    if (gt + 3 < TP2) {
      *(float4*)&hl[f * 260 + o4] = *(const float4*)src;
    } else {
#pragma unroll
      for (int k = 0; k < 4; ++k)
        hl[f * 260 + o4 + k] = (gt + k < TP2) ? src[k] : 0.f;
    }
  }
  hist[tid] = 0;
  __syncthreads();
  const int t = t0 + tid;
  if (t < LOUT) {
    double z = c0l;
    for (int f = 0; f < FILT; ++f) {
      const double* wr = &ws2l[f * WIN];
      z = fma((double)hl[f * 260 + tid + 0], wr[0], z);
      z = fma((double)hl[f * 260 + tid + 1], wr[1], z);
      z = fma((double)hl[f * 260 + tid + 2], wr[2], z);
      z = fma((double)hl[f * 260 + tid + 3], wr[3], z);
      z = fma((double)hl[f * 260 + tid + 4], wr[4], z);
    }
    z = z > 0.0 ? z : 0.0;
    double c = 1.0 / (1.0 + exp(-z));
    int iv = (int)ceil(c * 256.0) - 1;
    iv = min(max(iv, 0), DEMB - 1);
    idxp[b * LOUT + t] = iv;
    atomicAdd(&hist[iv], 1);
  }
  __syncthreads();
  atomicAdd(&count[b * DEMB + tid], hist[tid]);
}

// ---------------------------------------------------------------------------
// Kernel D: S[b,a,j] = sum_{l in chunk: idx[b,l]==j} W1[a,l]. 512 threads.
// ---------------------------------------------------------------------------
__global__ __launch_bounds__(512) void k_sbuild(
    const int* __restrict__ idxp, const float* __restrict__ w1t,
    float* __restrict__ Sg) {
  __shared__ float S[DA * 257];
  __shared__ int il[512];
  const int b = blockIdx.y, ch = blockIdx.x;
  const int tid = threadIdx.x;
  for (int i = tid; i < DA * 257; i += 512) S[i] = 0.f;
  const int l0 = ch * CS;
  for (int i = tid; i < CS; i += 512) il[i] = idxp[b * LOUT + l0 + i];
  __syncthreads();
  const int a = tid & 63, w = tid >> 6;
#pragma unroll 4
  for (int li = w; li < CS; li += 8) {
    int j = il[li];                          // wave-uniform broadcast
    float v = w1t[(l0 + li) * DA + a];       // coalesced 256B/wave
    atomicAdd(&S[a * 257 + j], v);
  }
  __syncthreads();
  for (int i = tid; i < DA * DEMB; i += 512) {
    int aa = i >> 8, j = i & 255;
    Sg[((b * NC + ch) * DA + aa) * DEMB + j] = S[aa * 257 + j];
  }
}

// ---------------------------------------------------------------------------
// Kernel E: fp32 GEMM T = (sum_ch S) @ emb256, epilogue A = sum_a W2 tanh(T).
// ---------------------------------------------------------------------------
__global__ __launch_bounds__(256) void k_gemmA(
    const float* __restrict__ Sg, const float* __restrict__ emb,
    const float* __restrict__ W2, float* __restrict__ Avec) {
  __shared__ float Al[16 * 64];
  __shared__ float Bl[16 * 64];
  __shared__ float red[16 * 64];
  const int b = blockIdx.x, c0 = blockIdx.y * 64;
  const int tid = threadIdx.x;
  const int tx = tid & 15, ty = tid >> 4;
  const int sa = tid >> 2, skq = (tid & 3) * 4;   // A staging map
  const int bk = tid >> 4, bseg = tid & 15;       // B staging map
  float acc[4][4] = {{0}};

  for (int kc = 0; kc < 16; ++kc) {
    const int kb = kc * 16;
    float4 v0 = *(const float4*)&Sg[((b * NC + 0) * DA + sa) * DEMB + kb + skq];
    float4 v1 = *(const float4*)&Sg[((b * NC + 1) * DA + sa) * DEMB + kb + skq];
    float4 v2 = *(const float4*)&Sg[((b * NC + 2) * DA + sa) * DEMB + kb + skq];
    float4 v3 = *(const float4*)&Sg[((b * NC + 3) * DA + sa) * DEMB + kb + skq];
    float4 sv = make_float4(v0.x + v1.x + v2.x + v3.x, v0.y + v1.y + v2.y + v3.y,
                            v0.z + v1.z + v2.z + v3.z, v0.w + v1.w + v2.w + v3.w);
    Al[(skq + 0) * 64 + sa] = sv.x;
    Al[(skq + 1) * 64 + sa] = sv.y;
    Al[(skq + 2) * 64 + sa] = sv.z;
    Al[(skq + 3) * 64 + sa] = sv.w;
    float4 e4 = *(const float4*)&emb[(kb + bk) * DEMB + c0 + bseg * 4];
    *(float4*)&Bl[bk * 64 + bseg * 4] = e4;
    __syncthreads();
#pragma unroll
    for (int k = 0; k < 16; ++k) {
      float4 av = *(const float4*)&Al[k * 64 + ty * 4];
      float4 bv = *(const float4*)&Bl[k * 64 + tx * 4];
      acc[0][0] = fmaf(av.x, bv.x, acc[0][0]); acc[0][1] = fmaf(av.x, bv.y, acc[0][1]);
      acc[0][2] = fmaf(av.x, bv.z, acc[0][2]); acc[0][3] = fmaf(av.x, bv.w, acc[0][3]);
      acc[1][0] = fmaf(av.y, bv.x, acc[1][0]); acc[1][1] = fmaf(av.y, bv.y, acc[1][1]);
      acc[1][2] = fmaf(av.y, bv.z, acc[1][2]); acc[1][3] = fmaf(av.y, bv.w, acc[1][3]);
      acc[2][0] = fmaf(av.z, bv.x, acc[2][0]); acc[2][1] = fmaf(av.z, bv.y, acc[2][1]);
      acc[2][2] = fmaf(av.z, bv.z, acc[2][2]); acc[2][3] = fmaf(av.z, bv.w, acc[2][3]);
      acc[3][0] = fmaf(av.w, bv.x, acc[3][0]); acc[3][1] = fmaf(av.w, bv.y, acc[3][1]);
      acc[3][2] = fmaf(av.w, bv.z, acc[3][2]); acc[3][3] = fmaf(av.w, bv.w, acc[3][3]);
    }
    __syncthreads();
  }
  float cs[4] = {0.f, 0.f, 0.f, 0.f};
#pragma unroll
  for (int r = 0; r < 4; ++r) {
    float wv = W2[ty * 4 + r];
#pragma unroll
    for (int j = 0; j < 4; ++j) cs[j] += tanhf(acc[r][j]) * wv;
  }
#pragma unroll
  for (int j = 0; j < 4; ++j) red[ty * 64 + tx * 4 + j] = cs[j];
  __syncthreads();
  if (tid < 64) {
    float s = 0.f;
#pragma unroll
    for (int q = 0; q < 16; ++q) s += red[q * 64 + tid];
    Avec[b * DEMB + c0 + tid] = s;
  }
}

// ---------------------------------------------------------------------------
// Kernel G: bucket softmax + fused att gather + barrier-free scores.
// ---------------------------------------------------------------------------
__global__ __launch_bounds__(256) void k_att(
    const float* __restrict__ Avec, const float* __restrict__ embT,
    const int* __restrict__ count, const float* __restrict__ linw,
    const float* __restrict__ linb, const int* __restrict__ idxp,
    float* __restrict__ att, float* __restrict__ scores) {
  __shared__ float Al[DEMB];
  __shared__ float pl[DEMB];
  __shared__ float scratch[4];
  const int b = blockIdx.x, j = threadIdx.x;
  Al[j] = Avec[b * DEMB + j];
  __syncthreads();
  float dot = 0.f;
  for (int d = 0; d < DEMB; ++d) dot = fmaf(embT[d * DEMB + j], Al[d], dot);
  const int cnt = count[b * DEMB + j];
  float v = (cnt > 0) ? dot : -3.4e38f;
#pragma unroll
  for (int off = 32; off > 0; off >>= 1) v = fmaxf(v, __shfl_down(v, off));
  if ((j & 63) == 0) scratch[j >> 6] = v;
  __syncthreads();
  const float m = fmaxf(fmaxf(scratch[0], scratch[1]), fmaxf(scratch[2], scratch[3]));
  __syncthreads();
  float e = (cnt > 0) ? expf(dot - m) : 0.f;
  float zs = e * (float)cnt;
#pragma unroll
  for (int off = 32; off > 0; off >>= 1) zs += __shfl_down(zs, off);
  if ((j & 63) == 0) scratch[j >> 6] = zs;
  __syncthreads();
  const float Z = scratch[0] + scratch[1] + scratch[2] + scratch[3];
  pl[j] = (cnt > 0) ? e / Z : 0.f;
  __syncthreads();
  for (int l = j; l < LOUT; l += 256)
    att[b * LOUT + l] = pl[idxp[b * LOUT + l]];
  const int w = j >> 6, lane = j & 63;
  for (int s = w; s < NSEC; s += 4) {
    float part = 0.f;
#pragma unroll
    for (int r = 0; r < 4; ++r)
      part = fmaf(Al[lane + r * 64], linw[s * DEMB + lane + r * 64], part);
#pragma unroll
    for (int off = 32; off > 0; off >>= 1) part += __shfl_down(part, off);
    if (lane == 0) scores[b * NSEC + s] = part + linb[s];
  }
}

// ---------------------------------------------------------------------------
extern "C" void kernel_launch(void* const* d_in, const int* in_sizes, int n_in,
                              void* d_out, int out_size, void* d_ws, size_t ws_size,
                              hipStream_t stream) {
  const float* x      = (const float*)d_in[0];
  const float* w1     = (const float*)d_in[1];
  const float* b1     = (const float*)d_in[2];
  const float* gamma  = (const float*)d_in[3];
  const float* beta   = (const float*)d_in[4];
  const float* w2     = (const float*)d_in[5];
  const float* b2     = (const float*)d_in[6];
  const float* emb    = (const float*)d_in[7];
  const float* W1     = (const float*)d_in[8];
  const float* W2     = (const float*)d_in[9];
  const float* linw   = (const float*)d_in[10];
  const float* linb   = (const float*)d_in[11];

  char* ws = (char*)d_ws;
  int*    count = (int*)   (ws + 0);           // 65536
  double* ws2g  = (double*)(ws + 65536);       // 320 doubles -> 68096
  double* c0g   = (double*)(ws + 68096);       // 8 bytes
  int*    idxp  = (int*)   (ws + 73728);       // -> 594944
  float*  w1t   = (float*) (ws + 594944);      // -> 1116160
  float*  embT  = (float*) (ws + 1116160);     // -> 1378304
  float*  Avec  = (float*) (ws + 1378304);     // -> 1443840
  float*  w1r   = (float*) (ws + 1443840);     // -> 1484800
  float*  h2    = (float*) (ws + 1484800);     // -> 34908160
  float*  Sg    = (float*) (ws + 34908160);    // -> 51685376
  // BN partials alias the Sg region: dead before k_sbuild writes Sg.
  double* bn_ps = (double*)(ws + 34908160);                  // 64*576*8
  double* bn_pq = (double*)(ws + 34908160 + 64 * NPS * 8);   //

  float* att_out    = (float*)d_out;
  float* scores_out = (float*)d_out + BATCH * LOUT;

  k_prep<<<dim3(152), 256, 0, stream>>>(W1, emb, w1, w1t, embT, w1r, count);
  k_conv1pool<<<dim3(NXB, 64), 256, 0, stream>>>(x, w1r, b1, h2, bn_ps, bn_pq);
  k_bnfin<<<dim3(1), 256, 0, stream>>>(bn_ps, bn_pq, gamma, beta, w2, b2,
                                       ws2g, c0g);
  k_conv2<<<dim3(8, 64), 256, 0, stream>>>(h2, ws2g, c0g, idxp, count);
  k_sbuild<<<dim3(NC, 64), 512, 0, stream>>>(idxp, w1t, Sg);
  k_gemmA<<<dim3(64, 4), 256, 0, stream>>>(Sg, emb, W2, Avec);
  k_att<<<dim3(64), 256, 0, stream>>>(Avec, embT, count, linw, linb, idxp,
                                      att_out, scores_out);
}

// Round 10
// 309.536 us; speedup vs baseline: 1.0838x; 1.0838x over previous
//
#include <hip/hip_runtime.h>
#include <math.h>

// Problem constants
#define BATCH 64
#define CIN   32
#define TIN   2048
#define FILT  64
#define WIN   5
#define TP1   2044   // conv1 out
#define TP2   2040   // pool out
#define LOUT  2036   // conv2 out
#define DEMB  256
#define DA    64
#define NSEC  11
#define NC    4      // S chunks
#define CS    509    // l's per chunk (4*509 = 2036)
#define NXB   5      // conv1 x-blocks
#define CT_TILE 504  // pool outputs per conv1 block (63 lanes x 8)
#define NPS   (BATCH * NXB)   // 320 BN partial slots per filter

// ---------------------------------------------------------------------------
// Kernel P: fused prep — zero count, W1 transpose, emb transpose, w1 repack.
// ---------------------------------------------------------------------------
__global__ __launch_bounds__(256) void k_prep(
    const float* __restrict__ W1, const float* __restrict__ emb,
    const float* __restrict__ w1, float* __restrict__ w1t,
    float* __restrict__ embT, float* __restrict__ w1r, int* __restrict__ count) {
  __shared__ float tl[64 * 65];
  int bk = blockIdx.x;
  const int tid = threadIdx.x;
  if (bk < 64) { count[bk * 256 + tid] = 0; return; }
  bk -= 64;
  if (bk < 32) {                       // W1 [64 x 2036] -> w1t [2036 x 64]
    const int l0 = bk * 64;
    const int lc = tid & 63, rq = tid >> 6;
    for (int a = rq; a < 64; a += 4)
      tl[a * 65 + lc] = (l0 + lc < LOUT) ? W1[a * LOUT + l0 + lc] : 0.f;
    __syncthreads();
    for (int lp = rq; lp < 64; lp += 4)
      if (l0 + lp < LOUT) w1t[(l0 + lp) * 64 + lc] = tl[lc * 65 + lp];
    return;
  }
  bk -= 32;
  if (bk < 16) {                       // emb [256 x 256] -> embT [256 x 256]
    const int j0 = (bk & 3) * 64, d0 = (bk >> 2) * 64;
    const int c = tid & 63, rq = tid >> 6;
    for (int j = rq; j < 64; j += 4) tl[j * 65 + c] = emb[(j0 + j) * DEMB + d0 + c];
    __syncthreads();
    for (int d = rq; d < 64; d += 4) embT[(d0 + d) * DEMB + j0 + c] = tl[c * 65 + d];
    return;
  }
  bk -= 16;
  {                                    // w1 [f][c][k] -> w1r [c][f*5+k]
    int i = bk * 256 + tid;            // 40*256 = 10240 exactly
    int c = i / 320, r = i - c * 320, f = r / 5, k = r - f * 5;
    w1r[i] = w1[f * (CIN * WIN) + c * WIN + k];
  }
}

// ---------------------------------------------------------------------------
// Kernel A: conv1 + bias + maxpool(5,1). R16 = exact R6/R8 best form:
// grid (5,64,4), 8 out/lane, 4 filters/wave, weights via wave-uniform
// s_load (NO LDS — the LDS data bus was the co-limiter, R6 +23us), plain
// immediate-use loop (compiler already hoists loads across iterations —
// R8's explicit pipeline was exactly null). z-merge CLOSED: 16x4 acc tile
// spills at VGPR 44 regardless of __launch_bounds__ (R7, R9).
// BN partials now stored TRANSPOSED [pslot][f] so k_bnfin reads coalesce.
// ---------------------------------------------------------------------------
__global__ __launch_bounds__(256) void k_conv1pool(
    const float* __restrict__ x, const float* __restrict__ w1r,
    const float* __restrict__ b1, float* __restrict__ h2,
    double* __restrict__ bn_ps, double* __restrict__ bn_pq) {
  const int b   = blockIdx.y;
  const int t0  = blockIdx.x * CT_TILE;
  const int tid = threadIdx.x;
  const int z   = blockIdx.z;

  const int tg   = tid & 63;
  const int tb   = tg * 8;
  const int wf0  = __builtin_amdgcn_readfirstlane(z * 16 + (tid >> 6) * 4);
  // wave-uniform weight base -> scalar (SGPR) address -> s_load weights.
  const float* wp = w1r + __builtin_amdgcn_readfirstlane(z * 80 + (tid >> 6) * 20);

  float acc[4][8];
#pragma unroll
  for (int ff = 0; ff < 4; ++ff) {
    float bias = b1[wf0 + ff];
#pragma unroll
    for (int j = 0; j < 8; ++j) acc[ff][j] = bias;
  }

  const float* xrow = x + (size_t)b * CIN * TIN + t0 + tb;
  const bool safe = (t0 + tb + 12) <= TIN;

  for (int c = 0; c < CIN; ++c) {
    float xw[12];
    if (safe) {
      float4 a0 = *(const float4*)(xrow + c * TIN);
      float4 a1 = *(const float4*)(xrow + c * TIN + 4);
      float4 a2 = *(const float4*)(xrow + c * TIN + 8);
      xw[0] = a0.x; xw[1] = a0.y; xw[2]  = a0.z; xw[3]  = a0.w;
      xw[4] = a1.x; xw[5] = a1.y; xw[6]  = a1.z; xw[7]  = a1.w;
      xw[8] = a2.x; xw[9] = a2.y; xw[10] = a2.z; xw[11] = a2.w;
    } else {
#pragma unroll
      for (int j = 0; j < 12; ++j) {
        int gt = t0 + tb + j;
        xw[j] = (gt < TIN) ? xrow[c * TIN + j] : 0.f;
      }
    }
#pragma unroll
    for (int q = 0; q < 5; ++q) {
      float4 wq = *(const float4*)(wp + c * 320 + q * 4);   // uniform -> s_load
      float wv[4] = {wq.x, wq.y, wq.z, wq.w};
#pragma unroll
      for (int r = 0; r < 4; ++r) {
        const int wi = q * 4 + r;          // compile-time
        const int ff = wi / 5, k = wi % 5; // static decode
#pragma unroll
        for (int j = 0; j < 8; ++j)
          acc[ff][j] = fmaf(xw[k + j], wv[r], acc[ff][j]);
      }
    }
  }

  const bool lanevalid = (tg < 63);
  const int t2b = t0 + tb;
  const int pslot = b * NXB + blockIdx.x;   // 0..319, unique per (b,bx)
#pragma unroll
  for (int ff = 0; ff < 4; ++ff) {
    float n0 = __shfl_down(acc[ff][0], 1);
    float n1 = __shfl_down(acc[ff][1], 1);
    float n2 = __shfl_down(acc[ff][2], 1);
    float n3 = __shfl_down(acc[ff][3], 1);
    float h[12] = {acc[ff][0], acc[ff][1], acc[ff][2], acc[ff][3],
                   acc[ff][4], acc[ff][5], acc[ff][6], acc[ff][7],
                   n0, n1, n2, n3};
    float o[8];
#pragma unroll
    for (int j = 0; j < 8; ++j) {
      float m = fmaxf(fmaxf(h[j], h[j + 1]), fmaxf(h[j + 2], h[j + 3]));
      o[j] = fmaxf(m, h[j + 4]);
    }
    const int f = wf0 + ff;

    // fused BN partial stats: wave-reduce fp64, plain store (no atomics).
    // Layout [pslot][f] — coalesced for k_bnfin's reads.
    double sd = 0.0, qd = 0.0;
    if (lanevalid) {
#pragma unroll
      for (int j = 0; j < 8; ++j) {
        if (t2b + j < TP2) {
          double v = (double)o[j];
          sd += v;
          qd = fma(v, v, qd);
        }
      }
    }
#pragma unroll
    for (int off = 32; off > 0; off >>= 1) {
      sd += __shfl_down(sd, off);
      qd += __shfl_down(qd, off);
    }
    if (tg == 0) {
      bn_ps[pslot * FILT + f] = sd;
      bn_pq[pslot * FILT + f] = qd;
    }

    if (lanevalid && (t2b + 7 < TP2)) {
      float* dst = &h2[((size_t)b * FILT + f) * TP2 + t2b];
      *(float4*)dst = make_float4(o[0], o[1], o[2], o[3]);
      *(float4*)(dst + 4) = make_float4(o[4], o[5], o[6], o[7]);
    } else if (lanevalid) {
#pragma unroll
      for (int j = 0; j < 8; ++j) {
        int t2 = t2b + j;
        if (t2 < TP2) h2[((size_t)b * FILT + f) * TP2 + t2] = o[j];
      }
    }
  }
}

// ---------------------------------------------------------------------------
// Kernel B2: single-block BN finalize. R16: partials are [pslot][64] so
// thread (f = tid&63) reads bn_ps[i*64+f] — lane-consecutive 512B/wave
// (was stride-2560B uncoalesced: 64 cache lines per wave-load, the likely
// 10-15us single-CU latency sink). Emits fused conv2 taps + constant.
// ---------------------------------------------------------------------------
__global__ __launch_bounds__(256) void k_bnfin(
    const double* __restrict__ bn_ps, const double* __restrict__ bn_pq,
    const float* __restrict__ gamma, const float* __restrict__ beta,
    const float* __restrict__ w2, const float* __restrict__ b2,
    double* __restrict__ ws2g, double* __restrict__ c0g) {
  __shared__ double sred[256], qred[256];
  const int tid = threadIdx.x;
  const int f = tid & 63, qq = tid >> 6;
  double s = 0.0, q = 0.0;
  for (int i = qq * (NPS / 4); i < (qq + 1) * (NPS / 4); ++i) {
    s += bn_ps[i * FILT + f];
    q += bn_pq[i * FILT + f];
  }
  sred[tid] = s; qred[tid] = q;
  __syncthreads();
  if (tid < 64) {
    double S = sred[tid] + sred[tid + 64] + sred[tid + 128] + sred[tid + 192];
    double Q = qred[tid] + qred[tid + 64] + qred[tid + 128] + qred[tid + 192];
    const double N = (double)(BATCH * TP2);
    double mu  = S / N;
    double var = Q / N - mu * mu;
    double sc  = (double)gamma[tid] / sqrt(var + 1e-5);
    double sh  = (double)beta[tid] - mu * sc;
    double wsum = 0.0;
#pragma unroll
    for (int k = 0; k < WIN; ++k) {
      double wv = (double)w2[tid * WIN + k];
      ws2g[tid * WIN + k] = sc * wv;
      wsum += wv;
    }
    double part = sh * wsum;
#pragma unroll
    for (int off = 32; off > 0; off >>= 1) part += __shfl_down(part, off);
    if (tid == 0) c0g[0] = part + (double)b2[0];
  }
}

// ---------------------------------------------------------------------------
// Kernel C: conv2 (frozen fp64 precision path). Taps come precomputed from
// k_bnfin; float4 LDS staging.
// ---------------------------------------------------------------------------
__global__ __launch_bounds__(256) void k_conv2(
    const float* __restrict__ h2, const double* __restrict__ ws2g,
    const double* __restrict__ c0g, int* __restrict__ idxp,
    int* __restrict__ count) {
  __shared__ float hl[FILT * 260];
  __shared__ int hist[DEMB];
  __shared__ double ws2l[FILT * WIN];
  __shared__ double c0l;
  const int b = blockIdx.y;
  const int t0 = blockIdx.x * 256;
  const int tid = threadIdx.x;

  for (int i = tid; i < FILT * WIN; i += 256) ws2l[i] = ws2g[i];
  if (tid == 0) c0l = c0g[0];

  // float4 staging: 64 filters x 65 float4 = 260 floats per row
  for (int i = tid; i < FILT * 65; i += 256) {
    int f = i / 65, o4 = (i - f * 65) * 4;
    int gt = t0 + o4;
    const float* src = &h2[((size_t)b * FILT + f) * TP2 + gt];
    if (gt + 3 < TP2) {
      *(float4*)&hl[f * 260 + o4] = *(const float4*)src;
    } else {
#pragma unroll
      for (int k = 0; k < 4; ++k)
        hl[f * 260 + o4 + k] = (gt + k < TP2) ? src[k] : 0.f;
    }
  }
  hist[tid] = 0;
  __syncthreads();
  const int t = t0 + tid;
  if (t < LOUT) {
    double z = c0l;
    for (int f = 0; f < FILT; ++f) {
      const double* wr = &ws2l[f * WIN];
      z = fma((double)hl[f * 260 + tid + 0], wr[0], z);
      z = fma((double)hl[f * 260 + tid + 1], wr[1], z);
      z = fma((double)hl[f * 260 + tid + 2], wr[2], z);
      z = fma((double)hl[f * 260 + tid + 3], wr[3], z);
      z = fma((double)hl[f * 260 + tid + 4], wr[4], z);
    }
    z = z > 0.0 ? z : 0.0;
    double c = 1.0 / (1.0 + exp(-z));
    int iv = (int)ceil(c * 256.0) - 1;
    iv = min(max(iv, 0), DEMB - 1);
    idxp[b * LOUT + t] = iv;
    atomicAdd(&hist[iv], 1);
  }
  __syncthreads();
  atomicAdd(&count[b * DEMB + tid], hist[tid]);
}

// ---------------------------------------------------------------------------
// Kernel D: S[b,a,j] = sum_{l in chunk: idx[b,l]==j} W1[a,l]. 512 threads.
// ---------------------------------------------------------------------------
__global__ __launch_bounds__(512) void k_sbuild(
    const int* __restrict__ idxp, const float* __restrict__ w1t,
    float* __restrict__ Sg) {
  __shared__ float S[DA * 257];
  __shared__ int il[512];
  const int b = blockIdx.y, ch = blockIdx.x;
  const int tid = threadIdx.x;
  for (int i = tid; i < DA * 257; i += 512) S[i] = 0.f;
  const int l0 = ch * CS;
  for (int i = tid; i < CS; i += 512) il[i] = idxp[b * LOUT + l0 + i];
  __syncthreads();
  const int a = tid & 63, w = tid >> 6;
#pragma unroll 4
  for (int li = w; li < CS; li += 8) {
    int j = il[li];                          // wave-uniform broadcast
    float v = w1t[(l0 + li) * DA + a];       // coalesced 256B/wave
    atomicAdd(&S[a * 257 + j], v);
  }
  __syncthreads();
  for (int i = tid; i < DA * DEMB; i += 512) {
    int aa = i >> 8, j = i & 255;
    Sg[((b * NC + ch) * DA + aa) * DEMB + j] = S[aa * 257 + j];
  }
}

// ---------------------------------------------------------------------------
// Kernel E: fp32 GEMM T = (sum_ch S) @ emb256, epilogue A = sum_a W2 tanh(T).
// ---------------------------------------------------------------------------
__global__ __launch_bounds__(256) void k_gemmA(
    const float* __restrict__ Sg, const float* __restrict__ emb,
    const float* __restrict__ W2, float* __restrict__ Avec) {
  __shared__ float Al[16 * 64];
  __shared__ float Bl[16 * 64];
  __shared__ float red[16 * 64];
  const int b = blockIdx.x, c0 = blockIdx.y * 64;
  const int tid = threadIdx.x;
  const int tx = tid & 15, ty = tid >> 4;
  const int sa = tid >> 2, skq = (tid & 3) * 4;   // A staging map
  const int bk = tid >> 4, bseg = tid & 15;       // B staging map
  float acc[4][4] = {{0}};

  for (int kc = 0; kc < 16; ++kc) {
    const int kb = kc * 16;
    float4 v0 = *(const float4*)&Sg[((b * NC + 0) * DA + sa) * DEMB + kb + skq];
    float4 v1 = *(const float4*)&Sg[((b * NC + 1) * DA + sa) * DEMB + kb + skq];
    float4 v2 = *(const float4*)&Sg[((b * NC + 2) * DA + sa) * DEMB + kb + skq];
    float4 v3 = *(const float4*)&Sg[((b * NC + 3) * DA + sa) * DEMB + kb + skq];
    float4 sv = make_float4(v0.x + v1.x + v2.x + v3.x, v0.y + v1.y + v2.y + v3.y,
                            v0.z + v1.z + v2.z + v3.z, v0.w + v1.w + v2.w + v3.w);
    Al[(skq + 0) * 64 + sa] = sv.x;
    Al[(skq + 1) * 64 + sa] = sv.y;
    Al[(skq + 2) * 64 + sa] = sv.z;
    Al[(skq + 3) * 64 + sa] = sv.w;
    float4 e4 = *(const float4*)&emb[(kb + bk) * DEMB + c0 + bseg * 4];
    *(float4*)&Bl[bk * 64 + bseg * 4] = e4;
    __syncthreads();
#pragma unroll
    for (int k = 0; k < 16; ++k) {
      float4 av = *(const float4*)&Al[k * 64 + ty * 4];
      float4 bv = *(const float4*)&Bl[k * 64 + tx * 4];
      acc[0][0] = fmaf(av.x, bv.x, acc[0][0]); acc[0][1] = fmaf(av.x, bv.y, acc[0][1]);
      acc[0][2] = fmaf(av.x, bv.z, acc[0][2]); acc[0][3] = fmaf(av.x, bv.w, acc[0][3]);
      acc[1][0] = fmaf(av.y, bv.x, acc[1][0]); acc[1][1] = fmaf(av.y, bv.y, acc[1][1]);
      acc[1][2] = fmaf(av.y, bv.z, acc[1][2]); acc[1][3] = fmaf(av.y, bv.w, acc[1][3]);
      acc[2][0] = fmaf(av.z, bv.x, acc[2][0]); acc[2][1] = fmaf(av.z, bv.y, acc[2][1]);
      acc[2][2] = fmaf(av.z, bv.z, acc[2][2]); acc[2][3] = fmaf(av.z, bv.w, acc[2][3]);
      acc[3][0] = fmaf(av.w, bv.x, acc[3][0]); acc[3][1] = fmaf(av.w, bv.y, acc[3][1]);
      acc[3][2] = fmaf(av.w, bv.z, acc[3][2]); acc[3][3] = fmaf(av.w, bv.w, acc[3][3]);
    }
    __syncthreads();
  }
  float cs[4] = {0.f, 0.f, 0.f, 0.f};
#pragma unroll
  for (int r = 0; r < 4; ++r) {
    float wv = W2[ty * 4 + r];
#pragma unroll
    for (int j = 0; j < 4; ++j) cs[j] += tanhf(acc[r][j]) * wv;
  }
#pragma unroll
  for (int j = 0; j < 4; ++j) red[ty * 64 + tx * 4 + j] = cs[j];
  __syncthreads();
  if (tid < 64) {
    float s = 0.f;
#pragma unroll
    for (int q = 0; q < 16; ++q) s += red[q * 64 + tid];
    Avec[b * DEMB + c0 + tid] = s;
  }
}

// ---------------------------------------------------------------------------
// Kernel G: bucket softmax + fused att gather + barrier-free scores.
// ---------------------------------------------------------------------------
__global__ __launch_bounds__(256) void k_att(
    const float* __restrict__ Avec, const float* __restrict__ embT,
    const int* __restrict__ count, const float* __restrict__ linw,
    const float* __restrict__ linb, const int* __restrict__ idxp,
    float* __restrict__ att, float* __restrict__ scores) {
  __shared__ float Al[DEMB];
  __shared__ float pl[DEMB];
  __shared__ float scratch[4];
  const int b = blockIdx.x, j = threadIdx.x;
  Al[j] = Avec[b * DEMB + j];
  __syncthreads();
  float dot = 0.f;
  for (int d = 0; d < DEMB; ++d) dot = fmaf(embT[d * DEMB + j], Al[d], dot);
  const int cnt = count[b * DEMB + j];
  float v = (cnt > 0) ? dot : -3.4e38f;
#pragma unroll
  for (int off = 32; off > 0; off >>= 1) v = fmaxf(v, __shfl_down(v, off));
  if ((j & 63) == 0) scratch[j >> 6] = v;
  __syncthreads();
  const float m = fmaxf(fmaxf(scratch[0], scratch[1]), fmaxf(scratch[2], scratch[3]));
  __syncthreads();
  float e = (cnt > 0) ? expf(dot - m) : 0.f;
  float zs = e * (float)cnt;
#pragma unroll
  for (int off = 32; off > 0; off >>= 1) zs += __shfl_down(zs, off);
  if ((j & 63) == 0) scratch[j >> 6] = zs;
  __syncthreads();
  const float Z = scratch[0] + scratch[1] + scratch[2] + scratch[3];
  pl[j] = (cnt > 0) ? e / Z : 0.f;
  __syncthreads();
  for (int l = j; l < LOUT; l += 256)
    att[b * LOUT + l] = pl[idxp[b * LOUT + l]];
  const int w = j >> 6, lane = j & 63;
  for (int s = w; s < NSEC; s += 4) {
    float part = 0.f;
#pragma unroll
    for (int r = 0; r < 4; ++r)
      part = fmaf(Al[lane + r * 64], linw[s * DEMB + lane + r * 64], part);
#pragma unroll
    for (int off = 32; off > 0; off >>= 1) part += __shfl_down(part, off);
    if (lane == 0) scores[b * NSEC + s] = part + linb[s];
  }
}

// ---------------------------------------------------------------------------
extern "C" void kernel_launch(void* const* d_in, const int* in_sizes, int n_in,
                              void* d_out, int out_size, void* d_ws, size_t ws_size,
                              hipStream_t stream) {
  const float* x      = (const float*)d_in[0];
  const float* w1     = (const float*)d_in[1];
  const float* b1     = (const float*)d_in[2];
  const float* gamma  = (const float*)d_in[3];
  const float* beta   = (const float*)d_in[4];
  const float* w2     = (const float*)d_in[5];
  const float* b2     = (const float*)d_in[6];
  const float* emb    = (const float*)d_in[7];
  const float* W1     = (const float*)d_in[8];
  const float* W2     = (const float*)d_in[9];
  const float* linw   = (const float*)d_in[10];
  const float* linb   = (const float*)d_in[11];

  char* ws = (char*)d_ws;
  int*    count = (int*)   (ws + 0);           // 65536
  double* ws2g  = (double*)(ws + 65536);       // 320 doubles -> 68096
  double* c0g   = (double*)(ws + 68096);       // 8 bytes
  int*    idxp  = (int*)   (ws + 73728);       // -> 594944
  float*  w1t   = (float*) (ws + 594944);      // -> 1116160
  float*  embT  = (float*) (ws + 1116160);     // -> 1378304
  float*  Avec  = (float*) (ws + 1378304);     // -> 1443840
  float*  w1r   = (float*) (ws + 1443840);     // -> 1484800
  float*  h2    = (float*) (ws + 1484800);     // -> 34908160
  float*  Sg    = (float*) (ws + 34908160);    // -> 51685376
  // BN partials alias the Sg region: dead before k_sbuild writes Sg.
  double* bn_ps = (double*)(ws + 34908160);                  // 320*64*8
  double* bn_pq = (double*)(ws + 34908160 + NPS * FILT * 8); //

  float* att_out    = (float*)d_out;
  float* scores_out = (float*)d_out + BATCH * LOUT;

  k_prep<<<dim3(152), 256, 0, stream>>>(W1, emb, w1, w1t, embT, w1r, count);
  k_conv1pool<<<dim3(NXB, 64, 4), 256, 0, stream>>>(x, w1r, b1, h2, bn_ps, bn_pq);
  k_bnfin<<<dim3(1), 256, 0, stream>>>(bn_ps, bn_pq, gamma, beta, w2, b2,
                                       ws2g, c0g);
  k_conv2<<<dim3(8, 64), 256, 0, stream>>>(h2, ws2g, c0g, idxp, count);
  k_sbuild<<<dim3(NC, 64), 512, 0, stream>>>(idxp, w1t, Sg);
  k_gemmA<<<dim3(64, 4), 256, 0, stream>>>(Sg, emb, W2, Avec);
  k_att<<<dim3(64), 256, 0, stream>>>(Avec, embT, count, linw, linb, idxp,
                                      att_out, scores_out);
}